// Round 1
// baseline (1036.590 us; speedup 1.0000x reference)
//
#include <hip/hip_runtime.h>

// RowAreaAttention: x:(16,4096,768) f32, w_qkv:(2304,768), w_proj:(768,768), b_proj:(768,)
// groups G=1024 (=16*64), 64 tokens each, 12 heads x 64 dim. out:(16,4096,768) f32.

#define NHEADS 12
#define SCALE  0.125f

typedef _Float16 h16;
typedef h16   half8 __attribute__((ext_vector_type(8)));
typedef float f32x4 __attribute__((ext_vector_type(4)));

__device__ __forceinline__ half8 loadw8(const h16* p) {
  return *(const half8*)p;
}
__device__ __forceinline__ half8 loadw8(const float* p) {
  const float4 a = *(const float4*)p;
  const float4 b = *(const float4*)(p + 4);
  half8 r;
  r[0] = (h16)a.x; r[1] = (h16)a.y; r[2] = (h16)a.z; r[3] = (h16)a.w;
  r[4] = (h16)b.x; r[5] = (h16)b.y; r[6] = (h16)b.z; r[7] = (h16)b.w;
  return r;
}

__global__ void prep_weights_kernel(const float* __restrict__ wq,
                                    const float* __restrict__ wp,
                                    h16* __restrict__ wq16,
                                    h16* __restrict__ wp16) {
  const int n1 = 2304 * 768;
  const int n2 = 768 * 768;
  for (int i = blockIdx.x * blockDim.x + threadIdx.x; i < n1 + n2;
       i += gridDim.x * blockDim.x) {
    if (i < n1) wq16[i] = (h16)wq[i];
    else        wp16[i - n1] = (h16)wp[i - n1];
  }
}

// One workgroup per group g. 8 waves (512 threads).
// LDS: xs  64x776 fp16 (x tile, padded: row stride 1552B -> +4 banks/row)
//      qs  64x72  fp16 (Q, reused as P after softmax)
//      ks  64x72  fp16 (K, reused as per-head attention output)
//      vt  64x72  fp16 (V transposed: [d][token] so PV B-frags are contiguous)
//      sS  64x68  f32  (logits)
template <typename WT>
__launch_bounds__(512, 2)
__global__ void fused_row_attn(const float* __restrict__ x,
                               const WT* __restrict__ wq,   // (2304,768) N-major, K contig
                               const WT* __restrict__ wp,   // (768,768)  N-major, K contig
                               const float* __restrict__ bias,
                               float* __restrict__ out) {
  __shared__ h16   xs[64][776];
  __shared__ h16   qs[64][72];
  __shared__ h16   ks[64][72];
  __shared__ h16   vt[64][72];
  __shared__ float sS[64][68];

  const int g    = blockIdx.x;
  const int tid  = threadIdx.x;
  const int wv   = tid >> 6;       // wave 0..7
  const int lane = tid & 63;
  const int l16  = lane & 15;
  const int kg   = lane >> 4;      // k-group 0..3

  // ---- stage x tile -> fp16 LDS (coalesced float4) ----
  const float* xg = x + (size_t)g * (64 * 768);
  #pragma unroll
  for (int i = 0; i < 24; ++i) {
    const int idx = tid + i * 512;          // 12288 float4s = 64x768
    const int row = idx / 192;
    const int c4  = (idx - row * 192) * 4;
    const float4 v = ((const float4*)xg)[idx];
    h16* p = &xs[row][c4];
    p[0] = (h16)v.x; p[1] = (h16)v.y; p[2] = (h16)v.z; p[3] = (h16)v.w;
  }

  // persistent proj accumulator: this wave owns out cols [wv*96, wv*96+96)
  f32x4 acc[4][6];
  #pragma unroll
  for (int a = 0; a < 4; ++a)
    #pragma unroll
    for (int b = 0; b < 6; ++b)
      acc[a][b] = (f32x4){0.f, 0.f, 0.f, 0.f};

  float bcol[6];
  #pragma unroll
  for (int cb = 0; cb < 6; ++cb) bcol[cb] = bias[wv * 96 + cb * 16 + l16];

  // QKV tiling: wave -> rows r0..r0+31, qkv-cols c0..c0+47 (of 192 per head)
  const int r0 = (wv & 1) * 32;
  const int c0 = (wv >> 1) * 48;
  // attention tiling: wave -> rows rS..rS+15, cols cS..cS+31 (of 64x64)
  const int rS = (wv >> 1) * 16;
  const int cS = (wv & 1) * 32;

  __syncthreads();

  for (int h = 0; h < NHEADS; ++h) {
    // ---------- QKV: xs(64x768) @ W_h^T(768x192) ----------
    f32x4 facc[2][3];
    #pragma unroll
    for (int a = 0; a < 2; ++a)
      #pragma unroll
      for (int b = 0; b < 3; ++b)
        facc[a][b] = (f32x4){0.f, 0.f, 0.f, 0.f};

    int wrow[3];
    #pragma unroll
    for (int cb = 0; cb < 3; ++cb) {
      const int n = c0 + cb * 16;           // 0..191; n>>6 : 0=q,1=k,2=v
      wrow[cb] = (n >> 6) * 768 + h * 64 + (n & 63) + l16;
    }
    for (int k0 = 0; k0 < 768; k0 += 32) {
      const half8 a0 = *(const half8*)&xs[r0 + l16][k0 + kg * 8];
      const half8 a1 = *(const half8*)&xs[r0 + 16 + l16][k0 + kg * 8];
      #pragma unroll
      for (int cb = 0; cb < 3; ++cb) {
        const half8 b = loadw8(wq + (size_t)wrow[cb] * 768 + k0 + kg * 8);
        facc[0][cb] = __builtin_amdgcn_mfma_f32_16x16x32_f16(a0, b, facc[0][cb], 0, 0, 0);
        facc[1][cb] = __builtin_amdgcn_mfma_f32_16x16x32_f16(a1, b, facc[1][cb], 0, 0, 0);
      }
    }
    // scatter C-frags: col<64 -> Q, <128 -> K, else -> V^T (branch wave-uniform)
    #pragma unroll
    for (int rb = 0; rb < 2; ++rb) {
      #pragma unroll
      for (int cb = 0; cb < 3; ++cb) {
        const int col  = c0 + cb * 16 + l16;
        const int rowb = r0 + rb * 16 + kg * 4;
        if (col < 64) {
          #pragma unroll
          for (int j = 0; j < 4; ++j) qs[rowb + j][col] = (h16)facc[rb][cb][j];
        } else if (col < 128) {
          #pragma unroll
          for (int j = 0; j < 4; ++j) ks[rowb + j][col - 64] = (h16)facc[rb][cb][j];
        } else {
          #pragma unroll
          for (int j = 0; j < 4; ++j) vt[col - 128][rowb + j] = (h16)facc[rb][cb][j];
        }
      }
    }
    __syncthreads();

    // ---------- S = Q K^T * scale ----------
    f32x4 sacc[2];
    sacc[0] = (f32x4){0.f, 0.f, 0.f, 0.f};
    sacc[1] = (f32x4){0.f, 0.f, 0.f, 0.f};
    #pragma unroll
    for (int k0 = 0; k0 < 64; k0 += 32) {
      const half8 aq  = *(const half8*)&qs[rS + l16][k0 + kg * 8];
      const half8 bk0 = *(const half8*)&ks[cS + l16][k0 + kg * 8];
      const half8 bk1 = *(const half8*)&ks[cS + 16 + l16][k0 + kg * 8];
      sacc[0] = __builtin_amdgcn_mfma_f32_16x16x32_f16(aq, bk0, sacc[0], 0, 0, 0);
      sacc[1] = __builtin_amdgcn_mfma_f32_16x16x32_f16(aq, bk1, sacc[1], 0, 0, 0);
    }
    #pragma unroll
    for (int t = 0; t < 2; ++t)
      #pragma unroll
      for (int j = 0; j < 4; ++j)
        sS[rS + kg * 4 + j][cS + t * 16 + l16] = sacc[t][j] * SCALE;
    __syncthreads();

    // ---------- softmax (fp32, 8 lanes per row) ----------
    {
      const int row = tid >> 3;
      const int j0  = (tid & 7) * 8;
      float v0[8];
      #pragma unroll
      for (int i = 0; i < 8; ++i) v0[i] = sS[row][j0 + i];
      float m = v0[0];
      #pragma unroll
      for (int i = 1; i < 8; ++i) m = fmaxf(m, v0[i]);
      m = fmaxf(m, __shfl_xor(m, 1));
      m = fmaxf(m, __shfl_xor(m, 2));
      m = fmaxf(m, __shfl_xor(m, 4));
      float e[8]; float s = 0.f;
      #pragma unroll
      for (int i = 0; i < 8; ++i) { e[i] = __expf(v0[i] - m); s += e[i]; }
      s += __shfl_xor(s, 1);
      s += __shfl_xor(s, 2);
      s += __shfl_xor(s, 4);
      const float inv = 1.0f / s;
      #pragma unroll
      for (int i = 0; i < 8; ++i) qs[row][j0 + i] = (h16)(e[i] * inv);  // P -> qs
    }
    __syncthreads();

    // ---------- O_h = P V ----------
    f32x4 oacc[2];
    oacc[0] = (f32x4){0.f, 0.f, 0.f, 0.f};
    oacc[1] = (f32x4){0.f, 0.f, 0.f, 0.f};
    #pragma unroll
    for (int k0 = 0; k0 < 64; k0 += 32) {
      const half8 ap  = *(const half8*)&qs[rS + l16][k0 + kg * 8];
      const half8 bv0 = *(const half8*)&vt[cS + l16][k0 + kg * 8];
      const half8 bv1 = *(const half8*)&vt[cS + 16 + l16][k0 + kg * 8];
      oacc[0] = __builtin_amdgcn_mfma_f32_16x16x32_f16(ap, bv0, oacc[0], 0, 0, 0);
      oacc[1] = __builtin_amdgcn_mfma_f32_16x16x32_f16(ap, bv1, oacc[1], 0, 0, 0);
    }
    #pragma unroll
    for (int t = 0; t < 2; ++t)
      #pragma unroll
      for (int j = 0; j < 4; ++j)
        ks[rS + kg * 4 + j][cS + t * 16 + l16] = (h16)oacc[t][j];   // O_h -> ks
    __syncthreads();

    // ---------- proj: acc += O_h(64x64) @ Wp_h^T(64x768) ----------
    #pragma unroll
    for (int k0 = 0; k0 < 64; k0 += 32) {
      half8 ah[4];
      #pragma unroll
      for (int rb = 0; rb < 4; ++rb)
        ah[rb] = *(const half8*)&ks[rb * 16 + l16][k0 + kg * 8];
      #pragma unroll
      for (int cb = 0; cb < 6; ++cb) {
        const int ocol = wv * 96 + cb * 16 + l16;
        const half8 bw = loadw8(wp + (size_t)ocol * 768 + h * 64 + k0 + kg * 8);
        #pragma unroll
        for (int rb = 0; rb < 4; ++rb)
          acc[rb][cb] = __builtin_amdgcn_mfma_f32_16x16x32_f16(ah[rb], bw, acc[rb][cb], 0, 0, 0);
      }
    }
    __syncthreads();
  }

  // ---------- epilogue: bias + store ----------
  float* og = out + (size_t)g * (64 * 768);
  #pragma unroll
  for (int rb = 0; rb < 4; ++rb) {
    #pragma unroll
    for (int cb = 0; cb < 6; ++cb) {
      const int col = wv * 96 + cb * 16 + l16;
      #pragma unroll
      for (int j = 0; j < 4; ++j) {
        const int row = rb * 16 + kg * 4 + j;
        og[(size_t)row * 768 + col] = acc[rb][cb][j] + bcol[cb];
      }
    }
  }
}

extern "C" void kernel_launch(void* const* d_in, const int* in_sizes, int n_in,
                              void* d_out, int out_size, void* d_ws, size_t ws_size,
                              hipStream_t stream) {
  const float* x     = (const float*)d_in[0];
  const float* wqkv  = (const float*)d_in[1];
  const float* wproj = (const float*)d_in[2];
  const float* bias  = (const float*)d_in[3];
  float* out = (float*)d_out;

  const size_t wq16_bytes = (size_t)2304 * 768 * sizeof(h16);
  const size_t wp16_bytes = (size_t)768 * 768 * sizeof(h16);

  if (ws_size >= wq16_bytes + wp16_bytes) {
    h16* wq16 = (h16*)d_ws;
    h16* wp16 = (h16*)((char*)d_ws + wq16_bytes);
    prep_weights_kernel<<<1024, 256, 0, stream>>>(wqkv, wproj, wq16, wp16);
    fused_row_attn<h16><<<1024, 512, 0, stream>>>(x, wq16, wp16, bias, out);
  } else {
    fused_row_attn<float><<<1024, 512, 0, stream>>>(x, wqkv, wproj, bias, out);
  }
}